// Round 8
// baseline (296.996 us; speedup 1.0000x reference)
//
#include <hip/hip_runtime.h>
#include <math.h>

// Problem constants (from reference)
constexpr int NN = 50000;
constexpr int EE = 800000;
constexpr int INC = 256, CC1 = 128, CC2 = 64;
constexpr int CAP = 56;   // CSR segment capacity; max in-degree ~35 (verified)

typedef short bf16x8 __attribute__((ext_vector_type(8)));
typedef float f32x4 __attribute__((ext_vector_type(4)));
typedef float fx4 __attribute__((ext_vector_type(4)));

__device__ __forceinline__ unsigned short f2bf(float f) {
    unsigned int u = __builtin_bit_cast(unsigned int, f);
    u = (u + 0x7FFFu + ((u >> 16) & 1u)) >> 16;   // RNE
    return (unsigned short)u;
}
__device__ __forceinline__ float bf2f(unsigned short u) {
    return __builtin_bit_cast(float, (unsigned int)u << 16);
}
__device__ __forceinline__ float bflo(unsigned int w) {
    return __builtin_bit_cast(float, w << 16);
}
__device__ __forceinline__ float bfhi(unsigned int w) {
    return __builtin_bit_cast(float, w & 0xFFFF0000u);
}
__device__ __forceinline__ unsigned int packbf2(float lo, float hi) {
    return (unsigned int)f2bf(lo) | ((unsigned int)f2bf(hi) << 16);
}
__device__ __forceinline__ float dinv_of(unsigned long long pk) {
    // deg = 1 (self loop) + fixed-point-24 weighted in-degree
    return rsqrtf(1.0f + (float)(unsigned int)pk * (1.0f / 16777216.0f));
}
// 4-byte edge payload: low 16 = src node (NN < 65536), high 16 = fp16(ew)
__device__ __forceinline__ float ew_of(unsigned int p) {
    return (float)__builtin_bit_cast(_Float16, (unsigned short)(p >> 16));
}

// ---------------- K1: prep — zero packed/stats + bf16 col-major weights -------
// w1t[col][k] for col<128 = W1[k][col]; col in [128,192) = Ws[k][col-128].
// w2t[col][k] = W2[k][col]. Staged per-block into LDS by the gemms (R6 showed
// direct-from-L2 B reads regress: 98 KB > 32 KB L1 → MFMA stalls on L2 latency).
__global__ void prep_kernel(unsigned long long* __restrict__ packed,
                            float* __restrict__ stats,
                            const float* __restrict__ W1, const float* __restrict__ Ws,
                            const float* __restrict__ W2,
                            unsigned short* __restrict__ w1t,
                            unsigned short* __restrict__ w2t) {
    const int b = blockIdx.x, t = threadIdx.x;
    int i = b * 256 + t;
    if (i < NN) packed[i] = 0ULL;
    if (i < 384) stats[i] = 0.0f;
    if (b < 192) {
        float v = (b < CC1) ? W1[(long long)t * CC1 + b]
                            : Ws[(long long)t * CC2 + (b - CC1)];
        w1t[b * 256 + t] = f2bf(v);
    } else {
        int n = b - 192;
        if (t < CC1) w2t[n * CC1 + t] = f2bf(W2[(long long)t * CC2 + n]);
    }
}

// ---------------- K2: gemm1 ([h1|skip] = x @ [W1|Ws]) + degree atomics --------
// Edge blocks: packed 64-bit atomic per edge + direct 4-byte pair scatter.
// Edge path is latency-chained (atomic → dependent scatter) → needs waves:
// 32-col LDS stages (16.9 KB, was 33 KB) double blocks/CU 4→8 for ALL blocks.
// x/col/ew are stream-once → nt loads (keep L2 for packed lines + pairs).
__global__ void __launch_bounds__(256) gemm1_rank_kernel(
        const float* __restrict__ A, const unsigned short* __restrict__ w1t,
        unsigned short* __restrict__ C1, unsigned short* __restrict__ C2,
        const int* __restrict__ row, const int* __restrict__ col,
        const float* __restrict__ ew,
        unsigned long long* __restrict__ packed,
        unsigned int* __restrict__ pairs, int gemm_blocks) {
    constexpr int K = INC, N1 = CC1, N2 = CC2, NT = N1 + N2;
    constexpr int TC = 32, PITCH = K + 8;          // 32 cols/stage, 264-short pitch
    __shared__ unsigned short Blds[TC * PITCH];    // 16896 B → 8 blocks/CU

    if ((int)blockIdx.x >= gemm_blocks) {
        int e = (blockIdx.x - gemm_blocks) * 256 + threadIdx.x;
        if (e < EE) {
            int c = __builtin_nontemporal_load(col + e);
            float w = __builtin_nontemporal_load(ew + e);
            unsigned int fx = __float2uint_rn(w * 16777216.0f);
            unsigned long long old =
                atomicAdd(&packed[c], (1ULL << 32) | (unsigned long long)fx);
            int rk = (int)(old >> 32);
            if (rk < CAP) {
                int r = __builtin_nontemporal_load(row + e);
                unsigned short hw =
                    __builtin_bit_cast(unsigned short, (_Float16)w);
                pairs[(long long)c * CAP + rk] =
                    (unsigned int)r | ((unsigned int)hw << 16);
            }
        }
        return;
    }

    const int tid = threadIdx.x;
    const int wave = tid >> 6, lane = tid & 63;
    const int quad = lane >> 4, nIdx = lane & 15;
    const int row0 = blockIdx.x * 64 + wave * 16;
    const int arow = row0 + nIdx;
    const int arow_c = (arow < NN) ? arow : (NN - 1);

    bf16x8 afrag[K / 32];
    {
        const float* ap = A + (long long)arow_c * K + quad * 8;
#pragma unroll
        for (int s = 0; s < K / 32; s++) {
            fx4 lo = __builtin_nontemporal_load((const fx4*)(ap + s * 32));
            fx4 hi = __builtin_nontemporal_load((const fx4*)(ap + s * 32 + 4));
            bf16x8 f;
            f[0] = (short)f2bf(lo[0]); f[1] = (short)f2bf(lo[1]);
            f[2] = (short)f2bf(lo[2]); f[3] = (short)f2bf(lo[3]);
            f[4] = (short)f2bf(hi[0]); f[5] = (short)f2bf(hi[1]);
            f[6] = (short)f2bf(hi[2]); f[7] = (short)f2bf(hi[3]);
            afrag[s] = f;
        }
    }

    for (int g0 = 0; g0 < NT; g0 += TC) {
        if (g0) __syncthreads();
        {
            int n = tid & 31;                    // col within 32-col stage
            int base = tid >> 5;                 // 8 threads per col
            const unsigned short* wsrc = w1t + (long long)(g0 + n) * 256;
#pragma unroll
            for (int i = 0; i < 4; i++) {
                int kc = base + 8 * i;
                *(bf16x8*)(&Blds[n * PITCH + kc * 8]) = *(const bf16x8*)(wsrc + kc * 8);
            }
        }
        __syncthreads();
#pragma unroll
        for (int t4 = 0; t4 < 2; t4++) {
            const unsigned short* bp = &Blds[(t4 * 16 + nIdx) * PITCH + quad * 8];
            f32x4 acc = {0.0f, 0.0f, 0.0f, 0.0f};
#pragma unroll
            for (int s = 0; s < K / 32; s++) {
                bf16x8 bf = *(const bf16x8*)(bp + s * 32);
                acc = __builtin_amdgcn_mfma_f32_16x16x32_bf16(afrag[s], bf, acc, 0, 0, 0);
            }
            int ocol = g0 + t4 * 16 + nIdx;   // C/D: col=lane&15, row=quad*4+reg
#pragma unroll
            for (int r = 0; r < 4; r++) {
                int orow = row0 + quad * 4 + r;
                if (orow < NN) {
                    if (ocol < N1)
                        C1[(long long)orow * N1 + ocol] = f2bf(acc[r]);
                    else
                        C2[(long long)orow * N2 + (ocol - N1)] = f2bf(acc[r]);
                }
            }
        }
    }
}

// ---------------- K4: gather1 (agg1 = Â h1 + b1) + BN1 stats (grid-stride) -------
// R0 engine (1024 blocks, 8-edge batches — measured best across R1-R4 ablations).
// 4-byte pairs; per-edge dinv computed on the fly from packed (400 KB,
// L2-resident — R6 showed this is neutral in the gathers; saves the dinv pass).
constexpr int CH1 = NN * 16 / 256;   // 3125 chunks, exact
__global__ void __launch_bounds__(256) gather1_kernel(
        const unsigned short* __restrict__ h, const unsigned long long* __restrict__ packed,
        const float* __restrict__ b1, const unsigned int* __restrict__ pairs,
        unsigned short* __restrict__ aggb, float* __restrict__ stats) {
    const int tid = threadIdx.x;
    const int part = tid & 15;
    const int c8 = part * 8;
    const int G = gridDim.x;

    float s[8] = {0,0,0,0,0,0,0,0}, q[8] = {0,0,0,0,0,0,0,0};
    float bb[8];
#pragma unroll
    for (int k = 0; k < 8; k++) bb[k] = b1[c8 + k];

    for (int c = blockIdx.x; c < CH1; c += G) {
        const int node = (c * 256 + tid) >> 4;
        unsigned long long pk = packed[node];
        int m = (int)(pk >> 32); if (m > CAP) m = CAP;
        float dc = dinv_of(pk);

        uint4 hv = *(const uint4*)(h + (long long)node * CC1 + c8);
        // t = dc*h_self + sum(dinv_r*ew*h_r); a = bb + dc*t
        float a0 = bflo(hv.x) * dc, a1 = bfhi(hv.x) * dc;
        float a2 = bflo(hv.y) * dc, a3 = bfhi(hv.y) * dc;
        float a4 = bflo(hv.z) * dc, a5 = bfhi(hv.z) * dc;
        float a6 = bflo(hv.w) * dc, a7 = bfhi(hv.w) * dc;

        const unsigned int* pp = pairs + (long long)node * CAP;
        int j = 0;
        for (; j + 8 <= m; j += 8) {
            uint4 pa = *(const uint4*)(pp + j);
            uint4 pb = *(const uint4*)(pp + j + 4);
            unsigned int p[8] = {pa.x, pa.y, pa.z, pa.w, pb.x, pb.y, pb.z, pb.w};
            int si[8];
#pragma unroll
            for (int i = 0; i < 8; i++) si[i] = (int)(p[i] & 0xFFFFu);
            unsigned long long pks[8];
#pragma unroll
            for (int i = 0; i < 8; i++) pks[i] = packed[si[i]];
            uint4 v[8];
#pragma unroll
            for (int i = 0; i < 8; i++)
                v[i] = *(const uint4*)(h + (long long)si[i] * CC1 + c8);
#pragma unroll
            for (int i = 0; i < 8; i++) {
                float w = ew_of(p[i]) * dinv_of(pks[i]);
                a0 += bflo(v[i].x) * w; a1 += bfhi(v[i].x) * w;
                a2 += bflo(v[i].y) * w; a3 += bfhi(v[i].y) * w;
                a4 += bflo(v[i].z) * w; a5 += bfhi(v[i].z) * w;
                a6 += bflo(v[i].w) * w; a7 += bfhi(v[i].w) * w;
            }
        }
        for (; j < m; j++) {
            unsigned int p = pp[j];
            int si = (int)(p & 0xFFFFu);
            float w = ew_of(p) * dinv_of(packed[si]);
            uint4 v = *(const uint4*)(h + (long long)si * CC1 + c8);
            a0 += bflo(v.x) * w; a1 += bfhi(v.x) * w;
            a2 += bflo(v.y) * w; a3 += bfhi(v.y) * w;
            a4 += bflo(v.z) * w; a5 += bfhi(v.z) * w;
            a6 += bflo(v.w) * w; a7 += bfhi(v.w) * w;
        }
        a0 = fmaf(a0, dc, bb[0]); a1 = fmaf(a1, dc, bb[1]);
        a2 = fmaf(a2, dc, bb[2]); a3 = fmaf(a3, dc, bb[3]);
        a4 = fmaf(a4, dc, bb[4]); a5 = fmaf(a5, dc, bb[5]);
        a6 = fmaf(a6, dc, bb[6]); a7 = fmaf(a7, dc, bb[7]);

        uint4 o;
        o.x = packbf2(a0, a1); o.y = packbf2(a2, a3);
        o.z = packbf2(a4, a5); o.w = packbf2(a6, a7);
        *(uint4*)(aggb + (long long)node * CC1 + c8) = o;

        s[0] += a0; q[0] += a0 * a0; s[1] += a1; q[1] += a1 * a1;
        s[2] += a2; q[2] += a2 * a2; s[3] += a3; q[3] += a3 * a3;
        s[4] += a4; q[4] += a4 * a4; s[5] += a5; q[5] += a5 * a5;
        s[6] += a6; q[6] += a6 * a6; s[7] += a7; q[7] += a7 * a7;
    }

    // once per block: wave shuffle (lanes 16 apart share channels) + LDS + atomics
#pragma unroll
    for (int k = 0; k < 8; k++) {
        s[k] += __shfl_xor(s[k], 16, 64); s[k] += __shfl_xor(s[k], 32, 64);
        q[k] += __shfl_xor(q[k], 16, 64); q[k] += __shfl_xor(q[k], 32, 64);
    }
    __shared__ float red[1024];
    const int wave = tid >> 6, lane = tid & 63;
    if (lane < 16) {
#pragma unroll
        for (int k = 0; k < 8; k++) {
            red[wave * 128 + lane * 8 + k] = s[k];
            red[512 + wave * 128 + lane * 8 + k] = q[k];
        }
    }
    __syncthreads();
    if (tid < CC1) {
        float as = 0.0f, aq = 0.0f;
#pragma unroll
        for (int w = 0; w < 4; w++) { as += red[w * 128 + tid]; aq += red[512 + w * 128 + tid]; }
        atomicAdd(&stats[tid], as);
        atomicAdd(&stats[128 + tid], aq);
    }
}

// ---------------- K5: gemm2 (h2 = gelu(bn1(agg1)) @ W2), BN1 params in-block -----
__global__ void __launch_bounds__(256) gemm2_kernel(
        const unsigned short* __restrict__ A, const unsigned short* __restrict__ w2t,
        unsigned short* __restrict__ C,
        const float* __restrict__ stats,
        const float* __restrict__ gamma, const float* __restrict__ beta) {
    constexpr int K = CC1, N = CC2;
    constexpr int KC = K / 8, PITCH = K + 8;
    __shared__ unsigned short Blds[N * PITCH];
    __shared__ float scL[K], shL[K];

    const int tid = threadIdx.x;
    if (tid < K) {
        float inv_n = 1.0f / (float)NN;
        float mu = stats[tid] * inv_n;
        float var = fmaxf(stats[128 + tid] * inv_n - mu * mu, 0.0f);
        float sc = gamma[tid] * rsqrtf(var + 1e-5f);
        scL[tid] = sc; shL[tid] = beta[tid] - mu * sc;
    }
    {
        int n = tid & 63;
        const unsigned short* wsrc = w2t + n * 128;
        for (int kc = tid >> 6; kc < KC; kc += 4)
            *(bf16x8*)(&Blds[n * PITCH + kc * 8]) = *(const bf16x8*)(wsrc + kc * 8);
    }
    __syncthreads();

    const int wave = tid >> 6, lane = tid & 63;
    const int quad = lane >> 4, nIdx = lane & 15;
    const int row0 = blockIdx.x * 64 + wave * 16;
    const int arow = row0 + nIdx;
    const int arow_c = (arow < NN) ? arow : (NN - 1);

    bf16x8 afrag[K / 32];
    {
        const unsigned short* ap = A + (long long)arow_c * K + quad * 8;
#pragma unroll
        for (int s = 0; s < K / 32; s++) {
            bf16x8 raw = *(const bf16x8*)(ap + s * 32);
            int kb = s * 32 + quad * 8;
            bf16x8 f;
#pragma unroll
            for (int j = 0; j < 8; j++) {
                float u = bf2f((unsigned short)raw[j]) * scL[kb + j] + shL[kb + j];
                float v = u * 0.5f * (1.0f + erff(u * 0.70710678f));
                f[j] = (short)f2bf(v);
            }
            afrag[s] = f;
        }
    }
#pragma unroll
    for (int t4 = 0; t4 < N / 16; t4++) {
        const unsigned short* bp = &Blds[(t4 * 16 + nIdx) * PITCH + quad * 8];
        f32x4 acc = {0.0f, 0.0f, 0.0f, 0.0f};
#pragma unroll
        for (int s = 0; s < K / 32; s++) {
            bf16x8 bf = *(const bf16x8*)(bp + s * 32);
            acc = __builtin_amdgcn_mfma_f32_16x16x32_bf16(afrag[s], bf, acc, 0, 0, 0);
        }
        int ocol = t4 * 16 + nIdx;
#pragma unroll
        for (int r = 0; r < 4; r++) {
            int orow = row0 + quad * 4 + r;
            if (orow < NN)
                C[(long long)orow * N + ocol] = f2bf(acc[r]);
        }
    }
}

// ---------------- K6: gather2 (agg2 = Â h2 + b2) + BN2 stats (grid-stride) -------
constexpr int CH2 = (NN * 8 + 255) / 256;   // 1563 chunks (last partial)
__global__ void __launch_bounds__(256) gather2_kernel(
        const unsigned short* __restrict__ h, const unsigned long long* __restrict__ packed,
        const float* __restrict__ b2, const unsigned int* __restrict__ pairs,
        unsigned short* __restrict__ aggb, float* __restrict__ stats) {
    const int tid = threadIdx.x;
    const int part = tid & 7;
    const int c8 = part * 8;
    const int G = gridDim.x;

    float s[8] = {0,0,0,0,0,0,0,0}, q[8] = {0,0,0,0,0,0,0,0};
    float bb[8];
#pragma unroll
    for (int k = 0; k < 8; k++) bb[k] = b2[c8 + k];

    for (int c = blockIdx.x; c < CH2; c += G) {
        const int node = (c * 256 + tid) >> 3;
        if (node >= NN) continue;
        unsigned long long pk = packed[node];
        int m = (int)(pk >> 32); if (m > CAP) m = CAP;
        float dc = dinv_of(pk);
        uint4 hv = *(const uint4*)(h + (long long)node * CC2 + c8);
        float a0 = bflo(hv.x) * dc, a1 = bfhi(hv.x) * dc;
        float a2 = bflo(hv.y) * dc, a3 = bfhi(hv.y) * dc;
        float a4 = bflo(hv.z) * dc, a5 = bfhi(hv.z) * dc;
        float a6 = bflo(hv.w) * dc, a7 = bfhi(hv.w) * dc;
        const unsigned int* pp = pairs + (long long)node * CAP;
        int j = 0;
        for (; j + 8 <= m; j += 8) {
            uint4 pa = *(const uint4*)(pp + j);
            uint4 pb = *(const uint4*)(pp + j + 4);
            unsigned int p[8] = {pa.x, pa.y, pa.z, pa.w, pb.x, pb.y, pb.z, pb.w};
            int si[8];
#pragma unroll
            for (int i = 0; i < 8; i++) si[i] = (int)(p[i] & 0xFFFFu);
            unsigned long long pks[8];
#pragma unroll
            for (int i = 0; i < 8; i++) pks[i] = packed[si[i]];
            uint4 v[8];
#pragma unroll
            for (int i = 0; i < 8; i++)
                v[i] = *(const uint4*)(h + (long long)si[i] * CC2 + c8);
#pragma unroll
            for (int i = 0; i < 8; i++) {
                float w = ew_of(p[i]) * dinv_of(pks[i]);
                a0 += bflo(v[i].x) * w; a1 += bfhi(v[i].x) * w;
                a2 += bflo(v[i].y) * w; a3 += bfhi(v[i].y) * w;
                a4 += bflo(v[i].z) * w; a5 += bfhi(v[i].z) * w;
                a6 += bflo(v[i].w) * w; a7 += bfhi(v[i].w) * w;
            }
        }
        for (; j < m; j++) {
            unsigned int p = pp[j];
            int si = (int)(p & 0xFFFFu);
            float w = ew_of(p) * dinv_of(packed[si]);
            uint4 v = *(const uint4*)(h + (long long)si * CC2 + c8);
            a0 += bflo(v.x) * w; a1 += bfhi(v.x) * w;
            a2 += bflo(v.y) * w; a3 += bfhi(v.y) * w;
            a4 += bflo(v.z) * w; a5 += bfhi(v.z) * w;
            a6 += bflo(v.w) * w; a7 += bfhi(v.w) * w;
        }
        a0 = fmaf(a0, dc, bb[0]); a1 = fmaf(a1, dc, bb[1]);
        a2 = fmaf(a2, dc, bb[2]); a3 = fmaf(a3, dc, bb[3]);
        a4 = fmaf(a4, dc, bb[4]); a5 = fmaf(a5, dc, bb[5]);
        a6 = fmaf(a6, dc, bb[6]); a7 = fmaf(a7, dc, bb[7]);
        uint4 o;
        o.x = packbf2(a0, a1); o.y = packbf2(a2, a3);
        o.z = packbf2(a4, a5); o.w = packbf2(a6, a7);
        *(uint4*)(aggb + (long long)node * CC2 + c8) = o;
        s[0] += a0; q[0] += a0 * a0; s[1] += a1; q[1] += a1 * a1;
        s[2] += a2; q[2] += a2 * a2; s[3] += a3; q[3] += a3 * a3;
        s[4] += a4; q[4] += a4 * a4; s[5] += a5; q[5] += a5 * a5;
        s[6] += a6; q[6] += a6 * a6; s[7] += a7; q[7] += a7 * a7;
    }

#pragma unroll
    for (int k = 0; k < 8; k++) {
        s[k] += __shfl_xor(s[k], 8, 64);
        s[k] += __shfl_xor(s[k], 16, 64);
        s[k] += __shfl_xor(s[k], 32, 64);
        q[k] += __shfl_xor(q[k], 8, 64);
        q[k] += __shfl_xor(q[k], 16, 64);
        q[k] += __shfl_xor(q[k], 32, 64);
    }
    __shared__ float red[512];
    const int wave = tid >> 6, lane = tid & 63;
    if (lane < 8) {
#pragma unroll
        for (int k = 0; k < 8; k++) {
            red[wave * 64 + lane * 8 + k] = s[k];
            red[256 + wave * 64 + lane * 8 + k] = q[k];
        }
    }
    __syncthreads();
    if (tid < CC2) {
        float as = 0.0f, aq = 0.0f;
#pragma unroll
        for (int w = 0; w < 4; w++) { as += red[w * 64 + tid]; aq += red[256 + w * 64 + tid]; }
        atomicAdd(&stats[256 + tid], as);
        atomicAdd(&stats[320 + tid], aq);
    }
}

// ---------------- K7: final out = bn2(agg2) + bs + skip (params in-block) ---------
__global__ void final_kernel(const unsigned short* __restrict__ agg2b,
                             const unsigned short* __restrict__ skipb,
                             const float* __restrict__ stats,
                             const float* __restrict__ gamma, const float* __restrict__ beta,
                             const float* __restrict__ bs, float* __restrict__ out) {
    __shared__ float sc[CC2], sh[CC2];
    if (threadIdx.x < CC2) {
        float inv_n = 1.0f / (float)NN;
        float mu = stats[256 + threadIdx.x] * inv_n;
        float var = fmaxf(stats[320 + threadIdx.x] * inv_n - mu * mu, 0.0f);
        float s = gamma[threadIdx.x] * rsqrtf(var + 1e-5f);
        sc[threadIdx.x] = s;
        sh[threadIdx.x] = beta[threadIdx.x] - mu * s + bs[threadIdx.x];
    }
    __syncthreads();
    int i2 = blockIdx.x * 256 + threadIdx.x;         // over NN * CC2/2, exact
    unsigned int av = ((const unsigned int*)agg2b)[i2];
    unsigned int sv = ((const unsigned int*)skipb)[i2];
    int c2 = (i2 & 31) * 2;
    float2 o;
    o.x = bflo(av) * sc[c2] + sh[c2] + bflo(sv);
    o.y = bfhi(av) * sc[c2 + 1] + sh[c2 + 1] + bfhi(sv);
    *(float2*)(out + 2 * (long long)i2) = o;
}

// ---------------- launch ----------------

extern "C" void kernel_launch(void* const* d_in, const int* in_sizes, int n_in,
                              void* d_out, int out_size, void* d_ws, size_t ws_size,
                              hipStream_t stream) {
    const float* x   = (const float*)d_in[0];
    const int*   ei  = (const int*)d_in[1];
    const float* ew  = (const float*)d_in[2];
    const float* W1  = (const float*)d_in[3];
    const float* b1  = (const float*)d_in[4];
    const float* W2  = (const float*)d_in[5];
    const float* b2  = (const float*)d_in[6];
    const float* g1  = (const float*)d_in[7];
    const float* be1 = (const float*)d_in[8];
    const float* g2  = (const float*)d_in[9];
    const float* be2 = (const float*)d_in[10];
    const float* Ws  = (const float*)d_in[11];
    const float* bs  = (const float*)d_in[12];
    float* out = (float*)d_out;

    const int* row = ei;            // edge_index[0]
    const int* col = ei + EE;       // edge_index[1]

    // workspace layout (h2b aliases h1b; agg2b aliases agg1b — phases are sequential)
    char* wp = (char*)d_ws;
    float* stats = (float*)wp;                                     // 4096 B (384 used)
    unsigned long long* packed = (unsigned long long*)(wp + 4096); // N*8
    char* q = wp + 4096 + (size_t)NN * 8;
    unsigned short* w1t = (unsigned short*)q; q += 192 * 256 * 2;        // 98 KB
    unsigned short* w2t = (unsigned short*)q; q += 64 * 128 * 2;         // 16 KB
    unsigned int* pairs = (unsigned int*)q;  q += (size_t)NN * CAP * 4;  // 11.2 MB
    unsigned short* h1b = (unsigned short*)q;  q += (size_t)NN * CC1 * 2; // 12.8 MB
    unsigned short* h2b = h1b;                                         // alias (h1 dead)
    unsigned short* agg1b = (unsigned short*)q; q += (size_t)NN * CC1 * 2; // 12.8 MB
    unsigned short* agg2b = agg1b;                                     // alias (agg1 dead)
    unsigned short* skipb = (unsigned short*)q; q += (size_t)NN * CC2 * 2; // 6.4 MB

    const int nb_G = (NN + 63) / 64;          // 782 gemm row-tiles
    const int nb_E = (EE + 255) / 256;        // 3125 edge chunks

    // prep: zero packed/stats + bf16 col-major weight tiles
    prep_kernel<<<256, 256, 0, stream>>>(packed, stats, W1, Ws, W2, w1t, w2t);

    // gemm1 (MFMA, 32-col LDS stages → 8 blocks/CU) + degree atomics + 4B scatter
    gemm1_rank_kernel<<<nb_G + nb_E, 256, 0, stream>>>(
        x, w1t, h1b, skipb, row, col, ew, packed, pairs, nb_G);

    // conv1 aggregation + BN1 stats (1024 blocks: measured-best balance)
    gather1_kernel<<<1024, 256, 0, stream>>>(h1b, packed, b1, pairs, agg1b, stats);

    // conv2 transform with fused BN1+GELU on A
    gemm2_kernel<<<nb_G, 256, 0, stream>>>(agg1b, w2t, h2b, stats, g1, be1);

    // conv2 aggregation + BN2 stats
    gather2_kernel<<<784, 256, 0, stream>>>(h2b, packed, b2, pairs, agg2b, stats);

    // out = bn2(agg2) + bs + skip
    final_kernel<<<NN * (CC2 / 2) / 256, 256, 0, stream>>>(
        agg2b, skipb, stats, g2, be2, bs, out);

    (void)in_sizes; (void)n_in; (void)out_size; (void)ws_size;
}

// Round 9
// 279.120 us; speedup vs baseline: 1.0640x; 1.0640x over previous
//
#include <hip/hip_runtime.h>
#include <math.h>

// Problem constants (from reference)
constexpr int NN = 50000;
constexpr int EE = 800000;
constexpr int INC = 256, CC1 = 128, CC2 = 64;
constexpr int CAP = 56;   // CSR segment capacity; max in-degree ~35 (verified)

typedef short bf16x8 __attribute__((ext_vector_type(8)));
typedef float f32x4 __attribute__((ext_vector_type(4)));

__device__ __forceinline__ unsigned short f2bf(float f) {
    unsigned int u = __builtin_bit_cast(unsigned int, f);
    u = (u + 0x7FFFu + ((u >> 16) & 1u)) >> 16;   // RNE
    return (unsigned short)u;
}
__device__ __forceinline__ float bf2f(unsigned short u) {
    return __builtin_bit_cast(float, (unsigned int)u << 16);
}
__device__ __forceinline__ float bflo(unsigned int w) {
    return __builtin_bit_cast(float, w << 16);
}
__device__ __forceinline__ float bfhi(unsigned int w) {
    return __builtin_bit_cast(float, w & 0xFFFF0000u);
}
__device__ __forceinline__ unsigned int packbf2(float lo, float hi) {
    return (unsigned int)f2bf(lo) | ((unsigned int)f2bf(hi) << 16);
}
__device__ __forceinline__ float dinv_of(unsigned long long pk) {
    // deg = 1 (self loop) + fixed-point-24 weighted in-degree
    return rsqrtf(1.0f + (float)(unsigned int)pk * (1.0f / 16777216.0f));
}
// 4-byte edge payload: low 16 = src node (NN < 65536), high 16 = fp16(ew)
__device__ __forceinline__ float ew_of(unsigned int p) {
    return (float)__builtin_bit_cast(_Float16, (unsigned short)(p >> 16));
}

// ---------------- K1: prep — zero packed/stats + bf16 col-major weights -------
// w1t[col][k] for col<128 = W1[k][col]; col in [128,192) = Ws[k][col-128].
// w2t[col][k] = W2[k][col]. Staged per-block into LDS by the gemms (R6 showed
// direct-from-L2 B reads regress: 98 KB > 32 KB L1 → MFMA stalls on L2 latency).
__global__ void prep_kernel(unsigned long long* __restrict__ packed,
                            float* __restrict__ stats,
                            const float* __restrict__ W1, const float* __restrict__ Ws,
                            const float* __restrict__ W2,
                            unsigned short* __restrict__ w1t,
                            unsigned short* __restrict__ w2t) {
    const int b = blockIdx.x, t = threadIdx.x;
    int i = b * 256 + t;
    if (i < NN) packed[i] = 0ULL;
    if (i < 384) stats[i] = 0.0f;
    if (b < 192) {
        float v = (b < CC1) ? W1[(long long)t * CC1 + b]
                            : Ws[(long long)t * CC2 + (b - CC1)];
        w1t[b * 256 + t] = f2bf(v);
    } else {
        int n = b - 192;
        if (t < CC1) w2t[n * CC1 + t] = f2bf(W2[(long long)t * CC2 + n]);
    }
}

// ---------------- K2: gemm1 ([h1|skip] = x @ [W1|Ws]) + degree atomics --------
// Edge blocks: TWO edges per thread — two INDEPENDENT {atomic → dependent
// scatter} chains issued back-to-back, doubling MLP on the ~600-900 cy atomic
// latency (R8 proved occupancy/LDS is not the limiter; this tests latency vs
// atomic-throughput bound). GEMM blocks: R7's LDS-staged 64-col bf16 B tile.
__global__ void __launch_bounds__(256) gemm1_rank_kernel(
        const float* __restrict__ A, const unsigned short* __restrict__ w1t,
        unsigned short* __restrict__ C1, unsigned short* __restrict__ C2,
        const int* __restrict__ row, const int* __restrict__ col,
        const float* __restrict__ ew,
        unsigned long long* __restrict__ packed,
        unsigned int* __restrict__ pairs, int gemm_blocks) {
    constexpr int K = INC, N1 = CC1, N2 = CC2, NT = N1 + N2;
    constexpr int KC = K / 8, PITCH = K + 8;
    __shared__ unsigned short Blds[64 * PITCH];

    if ((int)blockIdx.x >= gemm_blocks) {
        int e0 = (blockIdx.x - gemm_blocks) * 512 + threadIdx.x;
        int e1 = e0 + 256;
        if (e1 < EE) {
            int c0 = col[e0]; float w0 = ew[e0];
            int c1 = col[e1]; float w1 = ew[e1];
            unsigned int fx0 = __float2uint_rn(w0 * 16777216.0f);
            unsigned int fx1 = __float2uint_rn(w1 * 16777216.0f);
            unsigned long long old0 =
                atomicAdd(&packed[c0], (1ULL << 32) | (unsigned long long)fx0);
            unsigned long long old1 =
                atomicAdd(&packed[c1], (1ULL << 32) | (unsigned long long)fx1);
            int rk0 = (int)(old0 >> 32);
            int rk1 = (int)(old1 >> 32);
            if (rk0 < CAP) {
                int r = row[e0];
                unsigned short hw = __builtin_bit_cast(unsigned short, (_Float16)w0);
                pairs[(long long)c0 * CAP + rk0] =
                    (unsigned int)r | ((unsigned int)hw << 16);
            }
            if (rk1 < CAP) {
                int r = row[e1];
                unsigned short hw = __builtin_bit_cast(unsigned short, (_Float16)w1);
                pairs[(long long)c1 * CAP + rk1] =
                    (unsigned int)r | ((unsigned int)hw << 16);
            }
        } else if (e0 < EE) {
            int c = col[e0];
            float w = ew[e0];
            unsigned int fx = __float2uint_rn(w * 16777216.0f);
            unsigned long long old =
                atomicAdd(&packed[c], (1ULL << 32) | (unsigned long long)fx);
            int rk = (int)(old >> 32);
            if (rk < CAP) {
                int r = row[e0];
                unsigned short hw = __builtin_bit_cast(unsigned short, (_Float16)w);
                pairs[(long long)c * CAP + rk] =
                    (unsigned int)r | ((unsigned int)hw << 16);
            }
        }
        return;
    }

    const int tid = threadIdx.x;
    const int wave = tid >> 6, lane = tid & 63;
    const int quad = lane >> 4, nIdx = lane & 15;
    const int row0 = blockIdx.x * 64 + wave * 16;
    const int arow = row0 + nIdx;
    const int arow_c = (arow < NN) ? arow : (NN - 1);

    bf16x8 afrag[K / 32];
    {
        const float* ap = A + (long long)arow_c * K + quad * 8;
#pragma unroll
        for (int s = 0; s < K / 32; s++) {
            float4 lo = *(const float4*)(ap + s * 32);
            float4 hi = *(const float4*)(ap + s * 32 + 4);
            bf16x8 f;
            f[0] = (short)f2bf(lo.x); f[1] = (short)f2bf(lo.y);
            f[2] = (short)f2bf(lo.z); f[3] = (short)f2bf(lo.w);
            f[4] = (short)f2bf(hi.x); f[5] = (short)f2bf(hi.y);
            f[6] = (short)f2bf(hi.z); f[7] = (short)f2bf(hi.w);
            afrag[s] = f;
        }
    }

    for (int g0 = 0; g0 < NT; g0 += 64) {
        if (g0) __syncthreads();
        {
            int n = tid & 63;
            const unsigned short* wsrc = w1t + (long long)(g0 + n) * 256;
            for (int kc = tid >> 6; kc < KC; kc += 4)
                *(bf16x8*)(&Blds[n * PITCH + kc * 8]) = *(const bf16x8*)(wsrc + kc * 8);
        }
        __syncthreads();
#pragma unroll
        for (int t4 = 0; t4 < 4; t4++) {
            const unsigned short* bp = &Blds[(t4 * 16 + nIdx) * PITCH + quad * 8];
            f32x4 acc = {0.0f, 0.0f, 0.0f, 0.0f};
#pragma unroll
            for (int s = 0; s < K / 32; s++) {
                bf16x8 bf = *(const bf16x8*)(bp + s * 32);
                acc = __builtin_amdgcn_mfma_f32_16x16x32_bf16(afrag[s], bf, acc, 0, 0, 0);
            }
            int ocol = g0 + t4 * 16 + nIdx;   // C/D: col=lane&15, row=quad*4+reg
#pragma unroll
            for (int r = 0; r < 4; r++) {
                int orow = row0 + quad * 4 + r;
                if (orow < NN) {
                    if (ocol < N1)
                        C1[(long long)orow * N1 + ocol] = f2bf(acc[r]);
                    else
                        C2[(long long)orow * N2 + (ocol - N1)] = f2bf(acc[r]);
                }
            }
        }
    }
}

// ---------------- K3: dinv — tiny pass, degrees are final --------------------
// R8 proved gathers reading packed[] on the fly costs +8 µs (8B random loads,
// FETCH 84→88 MB) — the 4B dinv array is worth its 2 µs pass.
__global__ void dinv_kernel(const unsigned long long* __restrict__ packed,
                            float* __restrict__ dinv) {
    int i = blockIdx.x * 256 + threadIdx.x;
    if (i < NN) dinv[i] = dinv_of(packed[i]);
}

// ---------------- K4: gather1 (agg1 = Â h1 + b1) + BN1 stats (grid-stride) -------
// R0 engine (1024 blocks, 8-edge batches — measured best across R1-R4 ablations).
// 4-byte pairs: one 8-edge batch = 2× uint4 pair loads (32 B).
constexpr int CH1 = NN * 16 / 256;   // 3125 chunks, exact
__global__ void __launch_bounds__(256) gather1_kernel(
        const unsigned short* __restrict__ h, const unsigned long long* __restrict__ packed,
        const float* __restrict__ dinv,
        const float* __restrict__ b1, const unsigned int* __restrict__ pairs,
        unsigned short* __restrict__ aggb, float* __restrict__ stats) {
    const int tid = threadIdx.x;
    const int part = tid & 15;
    const int c8 = part * 8;
    const int G = gridDim.x;

    float s[8] = {0,0,0,0,0,0,0,0}, q[8] = {0,0,0,0,0,0,0,0};
    float bb[8];
#pragma unroll
    for (int k = 0; k < 8; k++) bb[k] = b1[c8 + k];

    for (int c = blockIdx.x; c < CH1; c += G) {
        const int node = (c * 256 + tid) >> 4;
        unsigned long long pk = packed[node];
        int m = (int)(pk >> 32); if (m > CAP) m = CAP;
        float dc = dinv_of(pk);

        uint4 hv = *(const uint4*)(h + (long long)node * CC1 + c8);
        // t = dc*h_self + sum(dinv_r*ew*h_r); a = bb + dc*t
        float a0 = bflo(hv.x) * dc, a1 = bfhi(hv.x) * dc;
        float a2 = bflo(hv.y) * dc, a3 = bfhi(hv.y) * dc;
        float a4 = bflo(hv.z) * dc, a5 = bfhi(hv.z) * dc;
        float a6 = bflo(hv.w) * dc, a7 = bfhi(hv.w) * dc;

        const unsigned int* pp = pairs + (long long)node * CAP;
        int j = 0;
        for (; j + 8 <= m; j += 8) {
            uint4 pa = *(const uint4*)(pp + j);
            uint4 pb = *(const uint4*)(pp + j + 4);
            unsigned int p[8] = {pa.x, pa.y, pa.z, pa.w, pb.x, pb.y, pb.z, pb.w};
            int si[8];
#pragma unroll
            for (int i = 0; i < 8; i++) si[i] = (int)(p[i] & 0xFFFFu);
            float dr[8];
#pragma unroll
            for (int i = 0; i < 8; i++) dr[i] = dinv[si[i]];
            uint4 v[8];
#pragma unroll
            for (int i = 0; i < 8; i++)
                v[i] = *(const uint4*)(h + (long long)si[i] * CC1 + c8);
#pragma unroll
            for (int i = 0; i < 8; i++) {
                float w = ew_of(p[i]) * dr[i];
                a0 += bflo(v[i].x) * w; a1 += bfhi(v[i].x) * w;
                a2 += bflo(v[i].y) * w; a3 += bfhi(v[i].y) * w;
                a4 += bflo(v[i].z) * w; a5 += bfhi(v[i].z) * w;
                a6 += bflo(v[i].w) * w; a7 += bfhi(v[i].w) * w;
            }
        }
        for (; j < m; j++) {
            unsigned int p = pp[j];
            int si = (int)(p & 0xFFFFu);
            float w = ew_of(p) * dinv[si];
            uint4 v = *(const uint4*)(h + (long long)si * CC1 + c8);
            a0 += bflo(v.x) * w; a1 += bfhi(v.x) * w;
            a2 += bflo(v.y) * w; a3 += bfhi(v.y) * w;
            a4 += bflo(v.z) * w; a5 += bfhi(v.z) * w;
            a6 += bflo(v.w) * w; a7 += bfhi(v.w) * w;
        }
        a0 = fmaf(a0, dc, bb[0]); a1 = fmaf(a1, dc, bb[1]);
        a2 = fmaf(a2, dc, bb[2]); a3 = fmaf(a3, dc, bb[3]);
        a4 = fmaf(a4, dc, bb[4]); a5 = fmaf(a5, dc, bb[5]);
        a6 = fmaf(a6, dc, bb[6]); a7 = fmaf(a7, dc, bb[7]);

        uint4 o;
        o.x = packbf2(a0, a1); o.y = packbf2(a2, a3);
        o.z = packbf2(a4, a5); o.w = packbf2(a6, a7);
        *(uint4*)(aggb + (long long)node * CC1 + c8) = o;

        s[0] += a0; q[0] += a0 * a0; s[1] += a1; q[1] += a1 * a1;
        s[2] += a2; q[2] += a2 * a2; s[3] += a3; q[3] += a3 * a3;
        s[4] += a4; q[4] += a4 * a4; s[5] += a5; q[5] += a5 * a5;
        s[6] += a6; q[6] += a6 * a6; s[7] += a7; q[7] += a7 * a7;
    }

    // once per block: wave shuffle (lanes 16 apart share channels) + LDS + atomics
#pragma unroll
    for (int k = 0; k < 8; k++) {
        s[k] += __shfl_xor(s[k], 16, 64); s[k] += __shfl_xor(s[k], 32, 64);
        q[k] += __shfl_xor(q[k], 16, 64); q[k] += __shfl_xor(q[k], 32, 64);
    }
    __shared__ float red[1024];
    const int wave = tid >> 6, lane = tid & 63;
    if (lane < 16) {
#pragma unroll
        for (int k = 0; k < 8; k++) {
            red[wave * 128 + lane * 8 + k] = s[k];
            red[512 + wave * 128 + lane * 8 + k] = q[k];
        }
    }
    __syncthreads();
    if (tid < CC1) {
        float as = 0.0f, aq = 0.0f;
#pragma unroll
        for (int w = 0; w < 4; w++) { as += red[w * 128 + tid]; aq += red[512 + w * 128 + tid]; }
        atomicAdd(&stats[tid], as);
        atomicAdd(&stats[128 + tid], aq);
    }
}

// ---------------- K5: gemm2 (h2 = gelu(bn1(agg1)) @ W2), BN1 params in-block -----
__global__ void __launch_bounds__(256) gemm2_kernel(
        const unsigned short* __restrict__ A, const unsigned short* __restrict__ w2t,
        unsigned short* __restrict__ C,
        const float* __restrict__ stats,
        const float* __restrict__ gamma, const float* __restrict__ beta) {
    constexpr int K = CC1, N = CC2;
    constexpr int KC = K / 8, PITCH = K + 8;
    __shared__ unsigned short Blds[N * PITCH];
    __shared__ float scL[K], shL[K];

    const int tid = threadIdx.x;
    if (tid < K) {
        float inv_n = 1.0f / (float)NN;
        float mu = stats[tid] * inv_n;
        float var = fmaxf(stats[128 + tid] * inv_n - mu * mu, 0.0f);
        float sc = gamma[tid] * rsqrtf(var + 1e-5f);
        scL[tid] = sc; shL[tid] = beta[tid] - mu * sc;
    }
    {
        int n = tid & 63;
        const unsigned short* wsrc = w2t + n * 128;
        for (int kc = tid >> 6; kc < KC; kc += 4)
            *(bf16x8*)(&Blds[n * PITCH + kc * 8]) = *(const bf16x8*)(wsrc + kc * 8);
    }
    __syncthreads();

    const int wave = tid >> 6, lane = tid & 63;
    const int quad = lane >> 4, nIdx = lane & 15;
    const int row0 = blockIdx.x * 64 + wave * 16;
    const int arow = row0 + nIdx;
    const int arow_c = (arow < NN) ? arow : (NN - 1);

    bf16x8 afrag[K / 32];
    {
        const unsigned short* ap = A + (long long)arow_c * K + quad * 8;
#pragma unroll
        for (int s = 0; s < K / 32; s++) {
            bf16x8 raw = *(const bf16x8*)(ap + s * 32);
            int kb = s * 32 + quad * 8;
            bf16x8 f;
#pragma unroll
            for (int j = 0; j < 8; j++) {
                float u = bf2f((unsigned short)raw[j]) * scL[kb + j] + shL[kb + j];
                float v = u * 0.5f * (1.0f + erff(u * 0.70710678f));
                f[j] = (short)f2bf(v);
            }
            afrag[s] = f;
        }
    }
#pragma unroll
    for (int t4 = 0; t4 < N / 16; t4++) {
        const unsigned short* bp = &Blds[(t4 * 16 + nIdx) * PITCH + quad * 8];
        f32x4 acc = {0.0f, 0.0f, 0.0f, 0.0f};
#pragma unroll
        for (int s = 0; s < K / 32; s++) {
            bf16x8 bf = *(const bf16x8*)(bp + s * 32);
            acc = __builtin_amdgcn_mfma_f32_16x16x32_bf16(afrag[s], bf, acc, 0, 0, 0);
        }
        int ocol = t4 * 16 + nIdx;
#pragma unroll
        for (int r = 0; r < 4; r++) {
            int orow = row0 + quad * 4 + r;
            if (orow < NN)
                C[(long long)orow * N + ocol] = f2bf(acc[r]);
        }
    }
}

// ---------------- K6: gather2 (agg2 = Â h2 + b2) + BN2 stats (grid-stride) -------
constexpr int CH2 = (NN * 8 + 255) / 256;   // 1563 chunks (last partial)
__global__ void __launch_bounds__(256) gather2_kernel(
        const unsigned short* __restrict__ h, const unsigned long long* __restrict__ packed,
        const float* __restrict__ dinv,
        const float* __restrict__ b2, const unsigned int* __restrict__ pairs,
        unsigned short* __restrict__ aggb, float* __restrict__ stats) {
    const int tid = threadIdx.x;
    const int part = tid & 7;
    const int c8 = part * 8;
    const int G = gridDim.x;

    float s[8] = {0,0,0,0,0,0,0,0}, q[8] = {0,0,0,0,0,0,0,0};
    float bb[8];
#pragma unroll
    for (int k = 0; k < 8; k++) bb[k] = b2[c8 + k];

    for (int c = blockIdx.x; c < CH2; c += G) {
        const int node = (c * 256 + tid) >> 3;
        if (node >= NN) continue;
        unsigned long long pk = packed[node];
        int m = (int)(pk >> 32); if (m > CAP) m = CAP;
        float dc = dinv_of(pk);
        uint4 hv = *(const uint4*)(h + (long long)node * CC2 + c8);
        float a0 = bflo(hv.x) * dc, a1 = bfhi(hv.x) * dc;
        float a2 = bflo(hv.y) * dc, a3 = bfhi(hv.y) * dc;
        float a4 = bflo(hv.z) * dc, a5 = bfhi(hv.z) * dc;
        float a6 = bflo(hv.w) * dc, a7 = bfhi(hv.w) * dc;
        const unsigned int* pp = pairs + (long long)node * CAP;
        int j = 0;
        for (; j + 8 <= m; j += 8) {
            uint4 pa = *(const uint4*)(pp + j);
            uint4 pb = *(const uint4*)(pp + j + 4);
            unsigned int p[8] = {pa.x, pa.y, pa.z, pa.w, pb.x, pb.y, pb.z, pb.w};
            int si[8];
#pragma unroll
            for (int i = 0; i < 8; i++) si[i] = (int)(p[i] & 0xFFFFu);
            float dr[8];
#pragma unroll
            for (int i = 0; i < 8; i++) dr[i] = dinv[si[i]];
            uint4 v[8];
#pragma unroll
            for (int i = 0; i < 8; i++)
                v[i] = *(const uint4*)(h + (long long)si[i] * CC2 + c8);
#pragma unroll
            for (int i = 0; i < 8; i++) {
                float w = ew_of(p[i]) * dr[i];
                a0 += bflo(v[i].x) * w; a1 += bfhi(v[i].x) * w;
                a2 += bflo(v[i].y) * w; a3 += bfhi(v[i].y) * w;
                a4 += bflo(v[i].z) * w; a5 += bfhi(v[i].z) * w;
                a6 += bflo(v[i].w) * w; a7 += bfhi(v[i].w) * w;
            }
        }
        for (; j < m; j++) {
            unsigned int p = pp[j];
            int si = (int)(p & 0xFFFFu);
            float w = ew_of(p) * dinv[si];
            uint4 v = *(const uint4*)(h + (long long)si * CC2 + c8);
            a0 += bflo(v.x) * w; a1 += bfhi(v.x) * w;
            a2 += bflo(v.y) * w; a3 += bfhi(v.y) * w;
            a4 += bflo(v.z) * w; a5 += bfhi(v.z) * w;
            a6 += bflo(v.w) * w; a7 += bfhi(v.w) * w;
        }
        a0 = fmaf(a0, dc, bb[0]); a1 = fmaf(a1, dc, bb[1]);
        a2 = fmaf(a2, dc, bb[2]); a3 = fmaf(a3, dc, bb[3]);
        a4 = fmaf(a4, dc, bb[4]); a5 = fmaf(a5, dc, bb[5]);
        a6 = fmaf(a6, dc, bb[6]); a7 = fmaf(a7, dc, bb[7]);
        uint4 o;
        o.x = packbf2(a0, a1); o.y = packbf2(a2, a3);
        o.z = packbf2(a4, a5); o.w = packbf2(a6, a7);
        *(uint4*)(aggb + (long long)node * CC2 + c8) = o;
        s[0] += a0; q[0] += a0 * a0; s[1] += a1; q[1] += a1 * a1;
        s[2] += a2; q[2] += a2 * a2; s[3] += a3; q[3] += a3 * a3;
        s[4] += a4; q[4] += a4 * a4; s[5] += a5; q[5] += a5 * a5;
        s[6] += a6; q[6] += a6 * a6; s[7] += a7; q[7] += a7 * a7;
    }

#pragma unroll
    for (int k = 0; k < 8; k++) {
        s[k] += __shfl_xor(s[k], 8, 64);
        s[k] += __shfl_xor(s[k], 16, 64);
        s[k] += __shfl_xor(s[k], 32, 64);
        q[k] += __shfl_xor(q[k], 8, 64);
        q[k] += __shfl_xor(q[k], 16, 64);
        q[k] += __shfl_xor(q[k], 32, 64);
    }
    __shared__ float red[512];
    const int wave = tid >> 6, lane = tid & 63;
    if (lane < 8) {
#pragma unroll
        for (int k = 0; k < 8; k++) {
            red[wave * 64 + lane * 8 + k] = s[k];
            red[256 + wave * 64 + lane * 8 + k] = q[k];
        }
    }
    __syncthreads();
    if (tid < CC2) {
        float as = 0.0f, aq = 0.0f;
#pragma unroll
        for (int w = 0; w < 4; w++) { as += red[w * 64 + tid]; aq += red[256 + w * 64 + tid]; }
        atomicAdd(&stats[256 + tid], as);
        atomicAdd(&stats[320 + tid], aq);
    }
}

// ---------------- K7: final out = bn2(agg2) + bs + skip (params in-block) ---------
__global__ void final_kernel(const unsigned short* __restrict__ agg2b,
                             const unsigned short* __restrict__ skipb,
                             const float* __restrict__ stats,
                             const float* __restrict__ gamma, const float* __restrict__ beta,
                             const float* __restrict__ bs, float* __restrict__ out) {
    __shared__ float sc[CC2], sh[CC2];
    if (threadIdx.x < CC2) {
        float inv_n = 1.0f / (float)NN;
        float mu = stats[256 + threadIdx.x] * inv_n;
        float var = fmaxf(stats[320 + threadIdx.x] * inv_n - mu * mu, 0.0f);
        float s = gamma[threadIdx.x] * rsqrtf(var + 1e-5f);
        sc[threadIdx.x] = s;
        sh[threadIdx.x] = beta[threadIdx.x] - mu * s + bs[threadIdx.x];
    }
    __syncthreads();
    int i2 = blockIdx.x * 256 + threadIdx.x;         // over NN * CC2/2, exact
    unsigned int av = ((const unsigned int*)agg2b)[i2];
    unsigned int sv = ((const unsigned int*)skipb)[i2];
    int c2 = (i2 & 31) * 2;
    float2 o;
    o.x = bflo(av) * sc[c2] + sh[c2] + bflo(sv);
    o.y = bfhi(av) * sc[c2 + 1] + sh[c2 + 1] + bfhi(sv);
    *(float2*)(out + 2 * (long long)i2) = o;
}

// ---------------- launch ----------------

extern "C" void kernel_launch(void* const* d_in, const int* in_sizes, int n_in,
                              void* d_out, int out_size, void* d_ws, size_t ws_size,
                              hipStream_t stream) {
    const float* x   = (const float*)d_in[0];
    const int*   ei  = (const int*)d_in[1];
    const float* ew  = (const float*)d_in[2];
    const float* W1  = (const float*)d_in[3];
    const float* b1  = (const float*)d_in[4];
    const float* W2  = (const float*)d_in[5];
    const float* b2  = (const float*)d_in[6];
    const float* g1  = (const float*)d_in[7];
    const float* be1 = (const float*)d_in[8];
    const float* g2  = (const float*)d_in[9];
    const float* be2 = (const float*)d_in[10];
    const float* Ws  = (const float*)d_in[11];
    const float* bs  = (const float*)d_in[12];
    float* out = (float*)d_out;

    const int* row = ei;            // edge_index[0]
    const int* col = ei + EE;       // edge_index[1]

    // workspace layout (h2b aliases h1b; agg2b aliases agg1b — phases are sequential)
    char* wp = (char*)d_ws;
    float* stats = (float*)wp;                                     // 4096 B (384 used)
    unsigned long long* packed = (unsigned long long*)(wp + 4096); // N*8
    char* q = wp + 4096 + (size_t)NN * 8;
    float* dinv = (float*)q;                 q += 256 * 1024;            // 200 KB used
    unsigned short* w1t = (unsigned short*)q; q += 192 * 256 * 2;        // 98 KB
    unsigned short* w2t = (unsigned short*)q; q += 64 * 128 * 2;         // 16 KB
    unsigned int* pairs = (unsigned int*)q;  q += (size_t)NN * CAP * 4;  // 11.2 MB
    unsigned short* h1b = (unsigned short*)q;  q += (size_t)NN * CC1 * 2; // 12.8 MB
    unsigned short* h2b = h1b;                                         // alias (h1 dead)
    unsigned short* agg1b = (unsigned short*)q; q += (size_t)NN * CC1 * 2; // 12.8 MB
    unsigned short* agg2b = agg1b;                                     // alias (agg1 dead)
    unsigned short* skipb = (unsigned short*)q; q += (size_t)NN * CC2 * 2; // 6.4 MB

    const int nb_G = (NN + 63) / 64;          // 782 gemm row-tiles
    const int nb_E2 = (EE + 511) / 512;       // 1563 edge chunks (2 edges/thread)

    // prep: zero packed/stats + bf16 col-major weight tiles
    prep_kernel<<<256, 256, 0, stream>>>(packed, stats, W1, Ws, W2, w1t, w2t);

    // gemm1 (MFMA, LDS-staged B) + degree atomics (2 chains/thread) + 4B scatter
    gemm1_rank_kernel<<<nb_G + nb_E2, 256, 0, stream>>>(
        x, w1t, h1b, skipb, row, col, ew, packed, pairs, nb_G);

    // dinv array (200 KB, L2-resident for the gathers)
    dinv_kernel<<<(NN + 255) / 256, 256, 0, stream>>>(packed, dinv);

    // conv1 aggregation + BN1 stats (1024 blocks: measured-best balance)
    gather1_kernel<<<1024, 256, 0, stream>>>(h1b, packed, dinv, b1, pairs, agg1b, stats);

    // conv2 transform with fused BN1+GELU on A
    gemm2_kernel<<<nb_G, 256, 0, stream>>>(agg1b, w2t, h2b, stats, g1, be1);

    // conv2 aggregation + BN2 stats
    gather2_kernel<<<784, 256, 0, stream>>>(h2b, packed, dinv, b2, pairs, agg2b, stats);

    // out = bn2(agg2) + bs + skip
    final_kernel<<<NN * (CC2 / 2) / 256, 256, 0, stream>>>(
        agg2b, skipb, stats, g2, be2, bs, out);

    (void)in_sizes; (void)n_in; (void)out_size; (void)ws_size;
}